// Round 7
// baseline (17.146 us; speedup 1.0000x reference)
//
#include <hip/hip_runtime.h>

// Two-kernel pipeline. Grid barriers on MI355X cost ~250us (contended
// device-scope RMWs + acquire-polls across 8 non-coherent XCDs — measured
// rounds 2/4), so two launches win.
//
// Kernel 1: per-node partial dots, 4 threads/node, 2 NODES PER THREAD
//   (W LDS reads reused across both nodes -> DS traffic per node halved):
//   tabA[n] = ( dot(h[n], W[0][0:128]),   dot(h[n], W[1][0:128])   )
//   tabB[n] = ( dot(h[n], W[0][128:256]), dot(h[n], W[1][128:256]) )
// Kernel 2: out[e] = tabA[src[e]] + tabB[dst[e]] + bias, 4 edges/thread.

__global__ __launch_bounds__(256) void node_dots_kernel(
    const float* __restrict__ h, const float* __restrict__ W,
    float2* __restrict__ tabA, float2* __restrict__ tabB, int n_nodes) {
  __shared__ float sW[512];  // W [2][256] = 2 KB
  const int tid = threadIdx.x;
  if (tid < 128) {
    reinterpret_cast<float4*>(sW)[tid] = reinterpret_cast<const float4*>(W)[tid];
  }
  __syncthreads();

  // Block covers 128 nodes: thread's nodes are n0 = blk*128 + (tid>>2)
  // and n1 = n0 + 64.
  const int node0 = blockIdx.x * 128 + (tid >> 2);
  if (node0 >= n_nodes) return;
  const int node1 = node0 + 64;
  const bool has1 = node1 < n_nodes;
  const int quad = tid & 3;
  const float* hrow0 = h + (size_t)node0 * 128;
  // If node1 OOB, alias to row0 (safe loads, result discarded at write).
  const float* hrow1 = h + (size_t)(has1 ? node1 : node0) * 128;

  float a0 = 0.f, a1 = 0.f, b0 = 0.f, b1 = 0.f;   // node0
  float c0 = 0.f, c1 = 0.f, e0 = 0.f, e1 = 0.f;   // node1
#pragma unroll
  for (int k = 0; k < 8; ++k) {
    // VERIFIED disjoint split: quad q handles d = 4q + 16k, k=0..7.
    const int d = quad * 4 + k * 16;
    const float4 h0 = *reinterpret_cast<const float4*>(hrow0 + d);
    const float4 h1 = *reinterpret_cast<const float4*>(hrow1 + d);
    const float4 w0 = *reinterpret_cast<const float4*>(sW + d);        // W[0][0:128]
    const float4 w1 = *reinterpret_cast<const float4*>(sW + 256 + d);  // W[1][0:128]
    const float4 w2 = *reinterpret_cast<const float4*>(sW + 128 + d);  // W[0][128:]
    const float4 w3 = *reinterpret_cast<const float4*>(sW + 384 + d);  // W[1][128:]
    a0 += h0.x * w0.x + h0.y * w0.y + h0.z * w0.z + h0.w * w0.w;
    a1 += h0.x * w1.x + h0.y * w1.y + h0.z * w1.z + h0.w * w1.w;
    b0 += h0.x * w2.x + h0.y * w2.y + h0.z * w2.z + h0.w * w2.w;
    b1 += h0.x * w3.x + h0.y * w3.y + h0.z * w3.z + h0.w * w3.w;
    c0 += h1.x * w0.x + h1.y * w0.y + h1.z * w0.z + h1.w * w0.w;
    c1 += h1.x * w1.x + h1.y * w1.y + h1.z * w1.z + h1.w * w1.w;
    e0 += h1.x * w2.x + h1.y * w2.y + h1.z * w2.z + h1.w * w2.w;
    e1 += h1.x * w3.x + h1.y * w3.y + h1.z * w3.z + h1.w * w3.w;
  }
  // Butterfly across the node's 4 lanes; all 4 lanes end with full sums.
  a0 += __shfl_xor(a0, 1); a0 += __shfl_xor(a0, 2);
  a1 += __shfl_xor(a1, 1); a1 += __shfl_xor(a1, 2);
  b0 += __shfl_xor(b0, 1); b0 += __shfl_xor(b0, 2);
  b1 += __shfl_xor(b1, 1); b1 += __shfl_xor(b1, 2);
  c0 += __shfl_xor(c0, 1); c0 += __shfl_xor(c0, 2);
  c1 += __shfl_xor(c1, 1); c1 += __shfl_xor(c1, 2);
  e0 += __shfl_xor(e0, 1); e0 += __shfl_xor(e0, 2);
  e1 += __shfl_xor(e1, 1); e1 += __shfl_xor(e1, 2);
  if (quad == 0) {
    tabA[node0] = make_float2(a0, a1);
    if (has1) tabA[node1] = make_float2(c0, c1);
  }
  if (quad == 1) {
    tabB[node0] = make_float2(b0, b1);
    if (has1) tabB[node1] = make_float2(e0, e1);
  }
}

__global__ __launch_bounds__(256) void edge_scores_kernel(
    const int* __restrict__ src, const int* __restrict__ dst,
    const float2* __restrict__ tabA, const float2* __restrict__ tabB,
    const float* __restrict__ bias, float2* __restrict__ out, int n_edges) {
  const float bx = bias[0], by = bias[1];
  const int nq = n_edges >> 2;  // groups of 4 edges
  const int p = blockIdx.x * blockDim.x + threadIdx.x;
  if (p < nq) {
    const int4 s4 = reinterpret_cast<const int4*>(src)[p];
    const int4 d4 = reinterpret_cast<const int4*>(dst)[p];
    const float2 a0 = tabA[s4.x];
    const float2 b0 = tabB[d4.x];
    const float2 a1 = tabA[s4.y];
    const float2 b1 = tabB[d4.y];
    const float2 a2 = tabA[s4.z];
    const float2 b2 = tabB[d4.z];
    const float2 a3 = tabA[s4.w];
    const float2 b3 = tabB[d4.w];
    float4* o4 = reinterpret_cast<float4*>(out) + p * 2;
    o4[0] = make_float4(a0.x + b0.x + bx, a0.y + b0.y + by,
                        a1.x + b1.x + bx, a1.y + b1.y + by);
    o4[1] = make_float4(a2.x + b2.x + bx, a2.y + b2.y + by,
                        a3.x + b3.x + bx, a3.y + b3.y + by);
  }
  // tail (n_edges % 4 != 0)
  if (p == 0) {
    for (int e = nq << 2; e < n_edges; ++e) {
      const float2 a = tabA[src[e]];
      const float2 b = tabB[dst[e]];
      out[e] = make_float2(a.x + b.x + bx, a.y + b.y + by);
    }
  }
}

// Fallback if d_ws is too small: direct per-edge gather + dot.
__global__ __launch_bounds__(256) void edge_direct_kernel(
    const float* __restrict__ h, const int* __restrict__ src,
    const int* __restrict__ dst, const float* __restrict__ W,
    const float* __restrict__ bias, float2* __restrict__ out, int n_edges) {
  __shared__ float sW[512];
  const int tid = threadIdx.x;
  if (tid < 128) {
    reinterpret_cast<float4*>(sW)[tid] = reinterpret_cast<const float4*>(W)[tid];
  }
  __syncthreads();
  const int e = blockIdx.x * blockDim.x + tid;
  if (e >= n_edges) return;
  const float* hu = h + (size_t)src[e] * 128;
  const float* hv = h + (size_t)dst[e] * 128;
  float s0 = bias[0], s1 = bias[1];
#pragma unroll 4
  for (int d = 0; d < 128; d += 4) {
    const float4 u = *reinterpret_cast<const float4*>(hu + d);
    const float4 v = *reinterpret_cast<const float4*>(hv + d);
    const float4 w00 = *reinterpret_cast<const float4*>(sW + d);
    const float4 w01 = *reinterpret_cast<const float4*>(sW + 128 + d);
    const float4 w10 = *reinterpret_cast<const float4*>(sW + 256 + d);
    const float4 w11 = *reinterpret_cast<const float4*>(sW + 384 + d);
    s0 += u.x * w00.x + u.y * w00.y + u.z * w00.z + u.w * w00.w
        + v.x * w01.x + v.y * w01.y + v.z * w01.z + v.w * w01.w;
    s1 += u.x * w10.x + u.y * w10.y + u.z * w10.z + u.w * w10.w
        + v.x * w11.x + v.y * w11.y + v.z * w11.z + v.w * w11.w;
  }
  out[e] = make_float2(s0, s1);
}

extern "C" void kernel_launch(void* const* d_in, const int* in_sizes, int n_in,
                              void* d_out, int out_size, void* d_ws, size_t ws_size,
                              hipStream_t stream) {
  const float* h    = (const float*)d_in[0];
  const int*   src  = (const int*)d_in[1];
  const int*   dst  = (const int*)d_in[2];
  const float* W    = (const float*)d_in[3];
  const float* bias = (const float*)d_in[4];
  float2* out = (float2*)d_out;

  const int n_nodes = in_sizes[0] / 128;
  const int n_edges = in_sizes[1];

  const size_t need = (size_t)n_nodes * 4 * sizeof(float);  // tabA + tabB
  if (ws_size >= need) {
    float2* tabA = (float2*)d_ws;
    float2* tabB = tabA + n_nodes;
    node_dots_kernel<<<(n_nodes + 127) / 128, 256, 0, stream>>>(h, W, tabA,
                                                                tabB, n_nodes);
    const int nq = (n_edges >> 2) > 0 ? (n_edges >> 2) : 1;
    edge_scores_kernel<<<(nq + 255) / 256, 256, 0, stream>>>(
        src, dst, tabA, tabB, bias, out, n_edges);
  } else {
    edge_direct_kernel<<<(n_edges + 255) / 256, 256, 0, stream>>>(
        h, src, dst, W, bias, out, n_edges);
  }
}